// Round 12
// baseline (1297.650 us; speedup 1.0000x reference)
//
#include <hip/hip_runtime.h>
#include <hip/hip_bf16.h>
#include <hip/hip_cooperative_groups.h>

namespace cg = cooperative_groups;

// GCN forward, MI355X. Round 12: ONE cooperative mega-kernel.
// R11 measured ~140us of kernel time inside 247us wall -> ~100us of
// inter-dispatch overhead (barrier packets + cross-XCD cache maintenance).
// All pipeline dependencies are grid-wide barriers, so the whole thing runs
// as one hipLaunchCooperativeKernel with grid.sync() between phases:
//   A0 zero(deg|desc|pooled|cnt)  -> sync
//   A  W->bf16 (frag-major) | batch->i32 | degree count  -> sync
//   B  decoupled-lookback scan -> row_ptr/cursor/dinv    -> sync
//   C  CSR fill (4B src) | X@W1 MFMA (x dinv epilogue)   -> sync
//   D/E/F aggemm layers (gather+relu -> LDS -> MFMA, agg-grid tasks) -> sync
//   G  agg_pool (LDS graph pool -> atomics)              -> sync
//   H  block 0: 64x16 @ 16x10 final linear
// __launch_bounds__(256,8) caps 64 VGPR -> 8 blocks/CU x 4 waves = 32
// waves/CU co-resident; grid from occupancy API (capture-safe).
//
// Lessons: R5 fuse at agg's grid. R7 no per-block device fences. R10/R11
// scatter writeback ~ line ownership migration per store (entry size and
// sharding don't matter) — stop attacking fill, attack dispatch overhead.

#define N_GRAPHS 64
#define N_CLASSES 10

typedef short bf8_t __attribute__((ext_vector_type(8)));
typedef float f4_t  __attribute__((ext_vector_type(4)));

__device__ __forceinline__ float b2f(unsigned int u) {
  return __uint_as_float(u << 16);
}
__device__ __forceinline__ unsigned short f2b(float f) {
  unsigned int x = __float_as_uint(f);
  x += 0x7fffu + ((x >> 16) & 1u);   // RNE (finite values only)
  return (unsigned short)(x >> 16);
}

__device__ __forceinline__ void block_detect(const unsigned int* __restrict__ xraw,
    const unsigned int* __restrict__ eraw, int* f32, int* i64) {
  __shared__ int c_bf, c_nz;
  if (threadIdx.x == 0) { c_bf = 0; c_nz = 0; }
  __syncthreads();
  unsigned int d = xraw[threadIdx.x & 255];
  int e = (int)(((d & 0xffffu) >> 7) & 0xff);
  if (e >= 100 && e <= 140) atomicAdd(&c_bf, 1);
  if (eraw && threadIdx.x < 64 && eraw[2 * threadIdx.x + 1] != 0u) atomicAdd(&c_nz, 1);
  __syncthreads();
  *f32 = (c_bf < 150) ? 1 : 0;
  if (i64) *i64 = (c_nz == 0) ? 1 : 0;
  __syncthreads();   // allow re-entry (c_bf reset next call)
}

struct WPtrs { const void* p[10]; };
static constexpr int WSEG[10] = {16384, 128, 8192, 64, 2048, 32, 512, 16, 160, 10};
static constexpr int WTOTAL   = 27546;
static constexpr int WOFF[10] = {0, 16384, 16512, 24704, 24768, 26816, 26848, 27360, 27376, 27536};

struct MegaArgs {
  const unsigned int* xraw;
  const int* eraw;
  const int* braw;
  WPtrs wp;
  unsigned short* wcan;
  int* b32;
  int* zbase_i; int nzd;          // zero region (dwords)
  int* deg;
  unsigned long long* desc;
  int* row_ptr;
  int* cursor;
  float* dinv;
  int* csr_src;
  unsigned short* hbufA;
  unsigned short* hbufB;
  float* pooled;
  float* cntf;
  void* out;
  int N, E, BW, BB, BEc, G1, nbS;
};

// ---- phase A task: weights | batch | degree count ----
__device__ void cvt_task(const MegaArgs& A, int t) {
  int f32, i64;
  block_detect(A.xraw, (const unsigned int*)A.eraw, &f32, &i64);
  if (t < A.BW) {
    int i = t * 256 + threadIdx.x;
    if (i >= WTOTAL) return;
    int off = i, s = 0;
    #pragma unroll
    for (int q = 0; q < 10; ++q) {
      if (s == 0 && off >= WSEG[q]) { off -= WSEG[q]; } else if (s == 0) { s = q + 1; }
    }
    s -= 1;
    int soff = off;
    if ((s & 1) == 0 && s <= 6) {           // W1..W4 -> fragment-major
      int KB, FOUT;
      if (s == 0)      { KB = 4; FOUT = 128; }
      else if (s == 2) { KB = 4; FOUT = 64; }
      else if (s == 4) { KB = 2; FOUT = 32; }
      else             { KB = 1; FOUT = 16; }
      int j = off & 7, l = (off >> 3) & 63, f = off >> 9;
      int ct = f / KB, kb = f - ct * KB;
      int k = kb * 32 + ((l >> 4) << 3) + j;
      int nn = ct * 16 + (l & 15);
      soff = k * FOUT + nn;
    }
    const void* p = A.wp.p[s];
    A.wcan[WOFF[s] + off] = f32 ? f2b(((const float*)p)[soff])
                                : ((const unsigned short*)p)[soff];
  } else if (t < A.BW + A.BB) {
    int i = (t - A.BW) * 256 + threadIdx.x;
    if (i < A.N) A.b32[i] = i64 ? A.braw[2 * i] : A.braw[i];
  } else {
    int e = (t - A.BW - A.BB) * 256 + threadIdx.x;
    if (e >= A.E) return;
    int d = i64 ? A.eraw[2 * (A.E + e)] : A.eraw[A.E + e];
    atomicAdd(&A.deg[d], 1);
  }
}

// ---- phase B: decoupled-lookback scan (task b == blockIdx, b < nbS) ----
__device__ void scan_task(const MegaArgs& A, int b) {
  __shared__ int ws[4];
  __shared__ int s_total;
  __shared__ unsigned int s_prev;
  const int tid = threadIdx.x, lane = tid & 63, wv = tid >> 6;
  const int i = b * 256 + tid;
  const int n = A.N;
  int v = (i < n) ? A.deg[i] : 0;
  int x = v;
  #pragma unroll
  for (int off = 1; off < 64; off <<= 1) {
    int y = __shfl_up(x, off, 64);
    if (lane >= off) x += y;
  }
  if (lane == 63) ws[wv] = x;
  __syncthreads();
  int wbase = 0;
  for (int w = 0; w < wv; ++w) wbase += ws[w];
  int incl = x + wbase;
  if (tid == 0) {
    int tot = ws[0] + ws[1] + ws[2] + ws[3];
    s_total = tot;
    unsigned long long st = (b == 0) ? (2ULL << 62) : (1ULL << 62);
    atomicExch(&A.desc[b], st | (unsigned long long)(unsigned int)tot);
    if (b == 0) s_prev = 0u;
  }
  __syncthreads();
  if (b > 0 && wv == 0) {
    unsigned int running = 0;
    int j = b - 1;
    while (true) {
      int idx = j - lane;
      unsigned long long dsc;
      if (idx >= 0) {
        do { dsc = atomicAdd(&A.desc[idx], 0ULL); } while ((dsc >> 62) == 0ULL);
      } else {
        dsc = (2ULL << 62);
      }
      unsigned long long ball = __ballot((dsc >> 62) == 2ULL);
      int fp = ball ? (__ffsll((unsigned long long)ball) - 1) : 64;
      unsigned int contrib = (lane <= fp) ? (unsigned int)(dsc & 0xffffffffULL) : 0u;
      #pragma unroll
      for (int o = 32; o; o >>= 1) contrib += __shfl_xor(contrib, o, 64);
      running += contrib;
      if (fp < 64) break;
      j -= 64;
    }
    if (lane == 0) {
      atomicExch(&A.desc[b], (2ULL << 62) |
                 (unsigned long long)(unsigned int)(running + (unsigned int)s_total));
      s_prev = running;
    }
  }
  __syncthreads();
  int tot = (int)s_prev + incl;
  if (i < n) {
    A.row_ptr[i + 1] = tot;
    A.cursor[i] = tot - v;
    A.dinv[i] = rsqrtf((float)v + 1.0f);
  }
  if (i == 0) A.row_ptr[0] = 0;
}

// ---- phase C task: fill (t<BEc) | gemm1 (t-BEc) ----
__device__ void fill_gemm1_task(const MegaArgs& A, int t) {
  int f32, i64;
  block_detect(A.xraw, (const unsigned int*)A.eraw, &f32, &i64);
  const int n = A.N, E = A.E;
  if (t < A.BEc) {
    int e = t * 256 + threadIdx.x;
    if (e < E) {
      int s, d;
      if (i64) { s = A.eraw[2 * e]; d = A.eraw[2 * (E + e)]; }
      else     { s = A.eraw[e];     d = A.eraw[E + e]; }
      int pos = atomicAdd(&A.cursor[d], 1);
      A.csr_src[pos] = s;
    }
    return;
  }
  const int b2 = t - A.BEc;
  const unsigned short* Wf = A.wcan + WOFF[0];
  const int l = threadIdx.x & 63;
  const int r16 = l & 15, quad = l >> 4;
  const int m0 = (b2 * 4 + (threadIdx.x >> 6)) * 32;
  if (m0 >= n) return;                       // per-wave, no syncs below
  bf8_t afrag[2][4];
  float dv[2][4];
  #pragma unroll
  for (int mt = 0; mt < 2; ++mt) {
    int node = m0 + mt * 16 + r16;
    int nc = node < n ? node : n - 1;
    #pragma unroll
    for (int r = 0; r < 4; ++r) {
      int nd = m0 + mt * 16 + quad * 4 + r;
      dv[mt][r] = A.dinv[nd < n ? nd : n - 1];
    }
    if (f32) {
      const float* xp = (const float*)A.xraw + (size_t)nc * 128 + quad * 8;
      #pragma unroll
      for (int kb = 0; kb < 4; ++kb) {
        const float4* p4 = (const float4*)(xp + kb * 32);
        float4 u0 = p4[0], u1 = p4[1];
        bf8_t a;
        a[0] = (short)f2b(u0.x); a[1] = (short)f2b(u0.y);
        a[2] = (short)f2b(u0.z); a[3] = (short)f2b(u0.w);
        a[4] = (short)f2b(u1.x); a[5] = (short)f2b(u1.y);
        a[6] = (short)f2b(u1.z); a[7] = (short)f2b(u1.w);
        afrag[mt][kb] = a;
      }
    } else {
      const unsigned short* xp = (const unsigned short*)A.xraw + (size_t)nc * 128 + quad * 8;
      #pragma unroll
      for (int kb = 0; kb < 4; ++kb)
        afrag[mt][kb] = *(const bf8_t*)(xp + kb * 32);
    }
  }
  #pragma unroll
  for (int ct = 0; ct < 8; ++ct) {
    bf8_t bfrag[4];
    #pragma unroll
    for (int kb = 0; kb < 4; ++kb)
      bfrag[kb] = *(const bf8_t*)(Wf + ((ct * 4 + kb) * 64 + l) * 8);
    #pragma unroll
    for (int mt = 0; mt < 2; ++mt) {
      f4_t acc = {0.f, 0.f, 0.f, 0.f};
      #pragma unroll
      for (int kb = 0; kb < 4; ++kb)
        acc = __builtin_amdgcn_mfma_f32_16x16x32_bf16(afrag[mt][kb], bfrag[kb], acc, 0, 0, 0);
      #pragma unroll
      for (int r = 0; r < 4; ++r) {
        int node = m0 + mt * 16 + quad * 4 + r;
        if (node < n)
          A.hbufA[(size_t)node * 128 + ct * 16 + r16] = f2b(acc[r] * dv[mt][r]);
      }
    }
  }
}

template<int DW> struct UVec { unsigned int d[DW]; };
template<int DW>
__device__ __forceinline__ UVec<DW> uload(const unsigned int* p) {
  UVec<DW> r;
  if constexpr (DW == 4) { uint4 v = *(const uint4*)p; r.d[0]=v.x; r.d[1]=v.y; r.d[2]=v.z; r.d[3]=v.w; }
  else if constexpr (DW == 2) { uint2 v = *(const uint2*)p; r.d[0]=v.x; r.d[1]=v.y; }
  else { r.d[0] = *p; }
  return r;
}
template<int DW>
__device__ __forceinline__ void ustore(unsigned int* p, const UVec<DW>& v) {
  if constexpr (DW == 4) { *(uint4*)p = make_uint4(v.d[0], v.d[1], v.d[2], v.d[3]); }
  else if constexpr (DW == 2) { *(uint2*)p = make_uint2(v.d[0], v.d[1]); }
  else { *p = v.d[0]; }
}

// ---- aggemm task body (leading __syncthreads protects LDS reuse) ----
template<int FIN, int FOUT, int LPG>
__device__ void aggemm_body(const unsigned short* __restrict__ Hin,
    const int* __restrict__ row_ptr, const int* __restrict__ csr_src,
    const float* __restrict__ dinv, const unsigned short* __restrict__ bias,
    const unsigned short* __restrict__ Wf, unsigned short* __restrict__ Hout,
    int n, int task, unsigned char* smemraw) {
  constexpr int DW  = FIN / LPG / 2;
  constexpr int NPB = 256 / LPG;
  constexpr int LD  = FIN + 8;
  constexpr int KB  = FIN / 32;
  constexpr int CT  = FOUT / 16;
  constexpr int MT  = NPB / 16;
  unsigned short* T = (unsigned short*)smemraw;
  __syncthreads();
  const int r = threadIdx.x / LPG, l = threadIdx.x % LPG;
  const int node0 = task * NPB;
  const int g = node0 + r;
  const unsigned int* H2 = (const unsigned int*)Hin;
  UVec<DW> o;
  #pragma unroll
  for (int d = 0; d < DW; ++d) o.d[d] = 0u;
  if (g < n) {
    float a[2 * DW];
    UVec<DW> hv = uload<DW>(H2 + (size_t)g * (FIN / 2) + l * DW);
    #pragma unroll
    for (int d = 0; d < DW; ++d) {          // self term H'[g]
      a[2*d]   = b2f(hv.d[d] & 0xffffu);
      a[2*d+1] = b2f(hv.d[d] >> 16);
    }
    const int e0 = row_ptr[g], e1 = row_ptr[g + 1];
    for (int base = e0; base < e1; base += LPG) {
      int cnt = e1 - base < LPG ? e1 - base : LPG;
      int my = csr_src[(base + l < e1) ? (base + l) : (e1 - 1)];
      for (int j = 0; j < cnt; ++j) {
        int s = __shfl(my, j, LPG);
        UVec<DW> v = uload<DW>(H2 + (size_t)s * (FIN / 2) + l * DW);
        #pragma unroll
        for (int d = 0; d < DW; ++d) {
          a[2*d]   += b2f(v.d[d] & 0xffffu);
          a[2*d+1] += b2f(v.d[d] >> 16);
        }
      }
    }
    float di = dinv[g];
    UVec<DW> bb = uload<DW>((const unsigned int*)bias + l * DW);
    #pragma unroll
    for (int d = 0; d < DW; ++d) {
      float lo = fmaxf(fmaf(a[2*d],   di, b2f(bb.d[d] & 0xffffu)), 0.f);
      float hi = fmaxf(fmaf(a[2*d+1], di, b2f(bb.d[d] >> 16)), 0.f);
      o.d[d] = (unsigned int)f2b(lo) | ((unsigned int)f2b(hi) << 16);
    }
  }
  ustore<DW>((unsigned int*)&T[r * LD + l * DW * 2], o);
  __syncthreads();
  const int w = threadIdx.x >> 6;
  if (w < MT * CT && node0 < n) {
    const int mt = w / CT, ct = w % CT;
    const int ll = threadIdx.x & 63;
    const int r16 = ll & 15, quad = ll >> 4;
    float dvv[4];
    #pragma unroll
    for (int rr = 0; rr < 4; ++rr) {
      int nd = node0 + mt * 16 + quad * 4 + rr;
      dvv[rr] = dinv[nd < n ? nd : n - 1];
    }
    bf8_t afrag[KB], bfrag[KB];
    #pragma unroll
    for (int kb = 0; kb < KB; ++kb) {
      afrag[kb] = *(const bf8_t*)(&T[(mt * 16 + r16) * LD + quad * 8 + kb * 32]);
      bfrag[kb] = *(const bf8_t*)(Wf + ((ct * KB + kb) * 64 + ll) * 8);
    }
    f4_t acc = {0.f, 0.f, 0.f, 0.f};
    #pragma unroll
    for (int kb = 0; kb < KB; ++kb)
      acc = __builtin_amdgcn_mfma_f32_16x16x32_bf16(afrag[kb], bfrag[kb], acc, 0, 0, 0);
    #pragma unroll
    for (int rr = 0; rr < 4; ++rr) {
      int node = node0 + mt * 16 + quad * 4 + rr;
      if (node < n)
        Hout[(size_t)node * FOUT + ct * 16 + r16] = f2b(acc[rr] * dvv[rr]);
    }
  }
}

// ---- agg_pool task body ----
__device__ void agg_pool_body(const MegaArgs& A, const unsigned short* __restrict__ Hin,
    const unsigned short* __restrict__ bias, int task, unsigned char* smemraw) {
  float* acc  = (float*)smemraw;                 // 64*16 floats
  float* ccnt = (float*)(smemraw + N_GRAPHS * 16 * 4);
  __syncthreads();
  for (int i = threadIdx.x; i < N_GRAPHS * 16; i += 256) acc[i] = 0.f;
  if (threadIdx.x < N_GRAPHS) ccnt[threadIdx.x] = 0.f;
  __syncthreads();
  const int n = A.N;
  const int r = threadIdx.x >> 3, l = threadIdx.x & 7;
  const int g = task * 32 + r;
  if (g < n) {
    const unsigned int* H2 = (const unsigned int*)Hin;
    unsigned int hv = H2[(size_t)g * 8 + l];
    float a0 = b2f(hv & 0xffffu);
    float a1 = b2f(hv >> 16);
    const int e0 = A.row_ptr[g], e1 = A.row_ptr[g + 1];
    for (int base = e0; base < e1; base += 8) {
      int cnt2 = e1 - base < 8 ? e1 - base : 8;
      int my = A.csr_src[(base + l < e1) ? (base + l) : (e1 - 1)];
      for (int j = 0; j < cnt2; ++j) {
        int s = __shfl(my, j, 8);
        unsigned int v = H2[(size_t)s * 8 + l];
        a0 += b2f(v & 0xffffu);
        a1 += b2f(v >> 16);
      }
    }
    float di = A.dinv[g];
    unsigned int bb = ((const unsigned int*)bias)[l];
    a0 = fmaxf(fmaf(a0, di, b2f(bb & 0xffffu)), 0.f);
    a1 = fmaxf(fmaf(a1, di, b2f(bb >> 16)), 0.f);
    int gb = A.b32[g];
    atomicAdd(&acc[gb * 16 + l * 2 + 0], a0);
    atomicAdd(&acc[gb * 16 + l * 2 + 1], a1);
    if (l == 0) atomicAdd(&ccnt[gb], 1.f);
  }
  __syncthreads();
  for (int i = threadIdx.x; i < N_GRAPHS * 16; i += 256)
    if (acc[i] != 0.f) atomicAdd(&A.pooled[i], acc[i]);
  if (threadIdx.x < N_GRAPHS && ccnt[threadIdx.x] != 0.f)
    atomicAdd(&A.cntf[threadIdx.x], ccnt[threadIdx.x]);
}

__device__ void final_body(const MegaArgs& A) {
  int f32;
  block_detect(A.xraw, nullptr, &f32, nullptr);
  const unsigned short* Wlin = A.wcan + WOFF[8];
  const unsigned short* blin = A.wcan + WOFF[9];
  for (int id = threadIdx.x; id < N_GRAPHS * N_CLASSES; id += 256) {
    int g = id / N_CLASSES, c = id - g * N_CLASSES;
    float inv = 1.0f / fmaxf(A.cntf[g], 1.0f);
    float a = b2f(blin[c]);
    #pragma unroll
    for (int f = 0; f < 16; ++f)
      a = fmaf(A.pooled[g * 16 + f] * inv, b2f(Wlin[f * N_CLASSES + c]), a);
    if (f32) ((float*)A.out)[id] = a;
    else     ((unsigned short*)A.out)[id] = f2b(a);
  }
}

__global__ __launch_bounds__(256, 8) void gcn_mega(MegaArgs A) {
  __shared__ __align__(16) unsigned char smem[6656];
  cg::grid_group grid = cg::this_grid();
  const int bid = blockIdx.x, G = gridDim.x;

  // A0: zero deg|desc|pooled|cnt
  for (int i = bid * 256 + threadIdx.x; i < A.nzd; i += G * 256) A.zbase_i[i] = 0;
  grid.sync();

  // A: weights | batch | degree count
  for (int t = bid; t < A.BW + A.BB + A.BEc; t += G) cvt_task(A, t);
  grid.sync();

  // B: scan (one task per block, nbS < G)
  if (bid < A.nbS) scan_task(A, bid);
  grid.sync();

  // C: CSR fill | gemm1
  for (int t = bid; t < A.BEc + A.G1; t += G) fill_gemm1_task(A, t);
  grid.sync();

  // D: layer 2 (agg over 128 -> gemm 128x64)
  {
    const int T1 = (A.N + 15) / 16;
    for (int t = bid; t < T1; t += G)
      aggemm_body<128, 64, 16>(A.hbufA, A.row_ptr, A.csr_src, A.dinv,
          A.wcan + WOFF[1], A.wcan + WOFF[2], A.hbufB, A.N, t, smem);
  }
  grid.sync();

  // E: layer 3 (agg over 64 -> gemm 64x32)
  {
    const int T2 = (A.N + 31) / 32;
    for (int t = bid; t < T2; t += G)
      aggemm_body<64, 32, 8>(A.hbufB, A.row_ptr, A.csr_src, A.dinv,
          A.wcan + WOFF[3], A.wcan + WOFF[4], A.hbufA, A.N, t, smem);
  }
  grid.sync();

  // F: layer 4 (agg over 32 -> gemm 32x16)
  {
    const int T3 = (A.N + 31) / 32;
    for (int t = bid; t < T3; t += G)
      aggemm_body<32, 16, 8>(A.hbufA, A.row_ptr, A.csr_src, A.dinv,
          A.wcan + WOFF[5], A.wcan + WOFF[6], A.hbufB, A.N, t, smem);
  }
  grid.sync();

  // G: last-layer agg + pool
  {
    const int TP = (A.N + 31) / 32;
    for (int t = bid; t < TP; t += G)
      agg_pool_body(A, A.hbufB, A.wcan + WOFF[7], t, smem);
  }
  grid.sync();

  // H: final linear
  if (bid == 0) final_body(A);
}

extern "C" void kernel_launch(void* const* d_in, const int* in_sizes, int n_in,
                              void* d_out, int out_size, void* d_ws, size_t ws_size,
                              hipStream_t stream) {
  const unsigned int* xraw = (const unsigned int*)d_in[0];
  const int* eraw          = (const int*)d_in[1];
  const int* braw          = (const int*)d_in[2];

  const int N = in_sizes[2];
  const int E = in_sizes[1] / 2;
  const int nbS = (N + 255) / 256;

  char* p = (char*)d_ws;
  auto alloc = [&](size_t bytes) -> void* {
    void* r = (void*)p;
    p += (bytes + 255) & ~(size_t)255;
    return r;
  };
  // zero region: deg | desc | pooled | cnt
  const size_t off_desc = ((size_t)N * 4 + 255) & ~(size_t)255;
  const size_t off_pool = (off_desc + (size_t)nbS * 8 + 255) & ~(size_t)255;
  const size_t ztotal   = off_pool + (N_GRAPHS * 16 + N_GRAPHS) * 4;
  char* zbase = (char*)alloc(ztotal);
  int*   deg    = (int*)zbase;
  unsigned long long* desc = (unsigned long long*)(zbase + off_desc);
  float* pooled = (float*)(zbase + off_pool);
  float* cntf   = pooled + N_GRAPHS * 16;

  int*   row_ptr  = (int*)  alloc((size_t)(N + 1) * 4);
  int*   cursor   = (int*)  alloc((size_t)N * 4);
  float* dinv     = (float*)alloc((size_t)N * 4);
  int*   batch32  = (int*)  alloc((size_t)N * 4);
  int*   csr_src  = (int*)  alloc((size_t)E * 4);
  unsigned short* wcan  = (unsigned short*)alloc((size_t)WTOTAL * 2);
  unsigned short* hbufA = (unsigned short*)alloc((size_t)N * 128 * 2);
  unsigned short* hbufB = (unsigned short*)alloc((size_t)N * 128 * 2);

  MegaArgs ma;
  ma.xraw = xraw; ma.eraw = eraw; ma.braw = braw;
  for (int i = 0; i < 10; ++i) ma.wp.p[i] = d_in[3 + i];
  ma.wcan = wcan; ma.b32 = batch32;
  ma.zbase_i = (int*)zbase; ma.nzd = (int)(ztotal / 4);
  ma.deg = deg; ma.desc = desc;
  ma.row_ptr = row_ptr; ma.cursor = cursor; ma.dinv = dinv;
  ma.csr_src = csr_src; ma.hbufA = hbufA; ma.hbufB = hbufB;
  ma.pooled = pooled; ma.cntf = cntf; ma.out = d_out;
  ma.N = N; ma.E = E;
  ma.BW = (WTOTAL + 255) / 256;
  ma.BB = (N + 255) / 256;
  ma.BEc = (E + 255) / 256;
  ma.G1 = (N + 127) / 128;
  ma.nbS = nbS;

  // Grid: co-residency-safe size from the occupancy API (deterministic,
  // capture-safe). Cap at 2048 (8 blocks/CU x 256 CUs at 64-VGPR bound).
  int blocksPerCU = 0;
  hipOccupancyMaxActiveBlocksPerMultiprocessor(&blocksPerCU, (const void*)gcn_mega, 256, 0);
  if (blocksPerCU < 1) blocksPerCU = 1;
  int grid = blocksPerCU * 256;
  if (grid > 2048) grid = 2048;

  void* args[] = { &ma };
  hipLaunchCooperativeKernel((const void*)gcn_mega, dim3(grid), dim3(256),
                             args, 0, stream);
}

// Round 13
// 827.507 us; speedup vs baseline: 1.5681x; 1.5681x over previous
//
#include <hip/hip_runtime.h>
#include <hip/hip_bf16.h>
#include <hip/hip_cooperative_groups.h>

namespace cg = cooperative_groups;

// GCN forward, MI355X. Round 13: cooperative mega-kernel, take 2.
// R12 failed from REGISTER SPILLS, not from grid.sync: __launch_bounds__
// (256,8) forced VGPR=32, the aggemm gather state (a[16] fp32 + frags)
// spilled to scratch -> 414 MB FETCH+WRITE (R11: ~110 MB) at 200 GB/s
// latency-bound = 2.1 ms. Fix: __launch_bounds__(256,4) (VGPR cap 128,
// bodies need ~52-80), LDS 4608 (true max), grid from occupancy API.
// Phases (grid.sync between):
//   A0 zero(deg|desc|pooled|cnt) | A W->bf16 frag-major + batch->i32 +
//   degree count | B decoupled-lookback scan | C CSR fill (4B src) +
//   X@W1 MFMA (x dinv) | D/E/F aggemm layers | G agg_pool | H final.
//
// Lessons: R5 fuse at agg's grid. R7 no per-block fences. R10/R11 scatter
// writeback ~ line migration per store. R12 launch_bounds 2nd arg is a
// VGPR cap in disguise — never set it below what the fattest body needs.

#define N_GRAPHS 64
#define N_CLASSES 10

typedef short bf8_t __attribute__((ext_vector_type(8)));
typedef float f4_t  __attribute__((ext_vector_type(4)));

__device__ __forceinline__ float b2f(unsigned int u) {
  return __uint_as_float(u << 16);
}
__device__ __forceinline__ unsigned short f2b(float f) {
  unsigned int x = __float_as_uint(f);
  x += 0x7fffu + ((x >> 16) & 1u);   // RNE (finite values only)
  return (unsigned short)(x >> 16);
}

__device__ __forceinline__ void block_detect(const unsigned int* __restrict__ xraw,
    const unsigned int* __restrict__ eraw, int* f32, int* i64) {
  __shared__ int c_bf, c_nz;
  if (threadIdx.x == 0) { c_bf = 0; c_nz = 0; }
  __syncthreads();
  unsigned int d = xraw[threadIdx.x & 255];
  int e = (int)(((d & 0xffffu) >> 7) & 0xff);
  if (e >= 100 && e <= 140) atomicAdd(&c_bf, 1);
  if (eraw && threadIdx.x < 64 && eraw[2 * threadIdx.x + 1] != 0u) atomicAdd(&c_nz, 1);
  __syncthreads();
  *f32 = (c_bf < 150) ? 1 : 0;
  if (i64) *i64 = (c_nz == 0) ? 1 : 0;
  __syncthreads();   // allow re-entry
}

struct WPtrs { const void* p[10]; };
static constexpr int WSEG[10] = {16384, 128, 8192, 64, 2048, 32, 512, 16, 160, 10};
static constexpr int WTOTAL   = 27546;
static constexpr int WOFF[10] = {0, 16384, 16512, 24704, 24768, 26816, 26848, 27360, 27376, 27536};

struct MegaArgs {
  const unsigned int* xraw;
  const int* eraw;
  const int* braw;
  WPtrs wp;
  unsigned short* wcan;
  int* b32;
  int* zbase_i; int nzd;
  int* deg;
  unsigned long long* desc;
  int* row_ptr;
  int* cursor;
  float* dinv;
  int* csr_src;
  unsigned short* hbufA;
  unsigned short* hbufB;
  float* pooled;
  float* cntf;
  void* out;
  int N, E, BW, BB, BEc, G1, nbS;
};

__device__ void cvt_task(const MegaArgs& A, int t) {
  int f32, i64;
  block_detect(A.xraw, (const unsigned int*)A.eraw, &f32, &i64);
  if (t < A.BW) {
    int i = t * 256 + threadIdx.x;
    if (i >= WTOTAL) return;
    int off = i, s = 0;
    #pragma unroll
    for (int q = 0; q < 10; ++q) {
      if (s == 0 && off >= WSEG[q]) { off -= WSEG[q]; } else if (s == 0) { s = q + 1; }
    }
    s -= 1;
    int soff = off;
    if ((s & 1) == 0 && s <= 6) {           // W1..W4 -> fragment-major
      int KB, FOUT;
      if (s == 0)      { KB = 4; FOUT = 128; }
      else if (s == 2) { KB = 4; FOUT = 64; }
      else if (s == 4) { KB = 2; FOUT = 32; }
      else             { KB = 1; FOUT = 16; }
      int j = off & 7, l = (off >> 3) & 63, f = off >> 9;
      int ct = f / KB, kb = f - ct * KB;
      int k = kb * 32 + ((l >> 4) << 3) + j;
      int nn = ct * 16 + (l & 15);
      soff = k * FOUT + nn;
    }
    const void* p = A.wp.p[s];
    A.wcan[WOFF[s] + off] = f32 ? f2b(((const float*)p)[soff])
                                : ((const unsigned short*)p)[soff];
  } else if (t < A.BW + A.BB) {
    int i = (t - A.BW) * 256 + threadIdx.x;
    if (i < A.N) A.b32[i] = i64 ? A.braw[2 * i] : A.braw[i];
  } else {
    int e = (t - A.BW - A.BB) * 256 + threadIdx.x;
    if (e >= A.E) return;
    int d = i64 ? A.eraw[2 * (A.E + e)] : A.eraw[A.E + e];
    atomicAdd(&A.deg[d], 1);
  }
}

__device__ void scan_task(const MegaArgs& A, int b) {
  __shared__ int ws[4];
  __shared__ int s_total;
  __shared__ unsigned int s_prev;
  const int tid = threadIdx.x, lane = tid & 63, wv = tid >> 6;
  const int i = b * 256 + tid;
  const int n = A.N;
  int v = (i < n) ? A.deg[i] : 0;
  int x = v;
  #pragma unroll
  for (int off = 1; off < 64; off <<= 1) {
    int y = __shfl_up(x, off, 64);
    if (lane >= off) x += y;
  }
  if (lane == 63) ws[wv] = x;
  __syncthreads();
  int wbase = 0;
  for (int w = 0; w < wv; ++w) wbase += ws[w];
  int incl = x + wbase;
  if (tid == 0) {
    int tot = ws[0] + ws[1] + ws[2] + ws[3];
    s_total = tot;
    unsigned long long st = (b == 0) ? (2ULL << 62) : (1ULL << 62);
    atomicExch(&A.desc[b], st | (unsigned long long)(unsigned int)tot);
    if (b == 0) s_prev = 0u;
  }
  __syncthreads();
  if (b > 0 && wv == 0) {
    unsigned int running = 0;
    int j = b - 1;
    while (true) {
      int idx = j - lane;
      unsigned long long dsc;
      if (idx >= 0) {
        do { dsc = atomicAdd(&A.desc[idx], 0ULL); } while ((dsc >> 62) == 0ULL);
      } else {
        dsc = (2ULL << 62);
      }
      unsigned long long ball = __ballot((dsc >> 62) == 2ULL);
      int fp = ball ? (__ffsll((unsigned long long)ball) - 1) : 64;
      unsigned int contrib = (lane <= fp) ? (unsigned int)(dsc & 0xffffffffULL) : 0u;
      #pragma unroll
      for (int o = 32; o; o >>= 1) contrib += __shfl_xor(contrib, o, 64);
      running += contrib;
      if (fp < 64) break;
      j -= 64;
    }
    if (lane == 0) {
      atomicExch(&A.desc[b], (2ULL << 62) |
                 (unsigned long long)(unsigned int)(running + (unsigned int)s_total));
      s_prev = running;
    }
  }
  __syncthreads();
  int tot = (int)s_prev + incl;
  if (i < n) {
    A.row_ptr[i + 1] = tot;
    A.cursor[i] = tot - v;
    A.dinv[i] = rsqrtf((float)v + 1.0f);
  }
  if (i == 0) A.row_ptr[0] = 0;
}

__device__ void fill_gemm1_task(const MegaArgs& A, int t) {
  int f32, i64;
  block_detect(A.xraw, (const unsigned int*)A.eraw, &f32, &i64);
  const int n = A.N, E = A.E;
  if (t < A.BEc) {
    int e = t * 256 + threadIdx.x;
    if (e < E) {
      int s, d;
      if (i64) { s = A.eraw[2 * e]; d = A.eraw[2 * (E + e)]; }
      else     { s = A.eraw[e];     d = A.eraw[E + e]; }
      int pos = atomicAdd(&A.cursor[d], 1);
      A.csr_src[pos] = s;
    }
    return;
  }
  const int b2 = t - A.BEc;
  const unsigned short* Wf = A.wcan + WOFF[0];
  const int l = threadIdx.x & 63;
  const int r16 = l & 15, quad = l >> 4;
  const int m0 = (b2 * 4 + (threadIdx.x >> 6)) * 32;
  if (m0 >= n) return;
  bf8_t afrag[2][4];
  float dv[2][4];
  #pragma unroll
  for (int mt = 0; mt < 2; ++mt) {
    int node = m0 + mt * 16 + r16;
    int nc = node < n ? node : n - 1;
    #pragma unroll
    for (int r = 0; r < 4; ++r) {
      int nd = m0 + mt * 16 + quad * 4 + r;
      dv[mt][r] = A.dinv[nd < n ? nd : n - 1];
    }
    if (f32) {
      const float* xp = (const float*)A.xraw + (size_t)nc * 128 + quad * 8;
      #pragma unroll
      for (int kb = 0; kb < 4; ++kb) {
        const float4* p4 = (const float4*)(xp + kb * 32);
        float4 u0 = p4[0], u1 = p4[1];
        bf8_t a;
        a[0] = (short)f2b(u0.x); a[1] = (short)f2b(u0.y);
        a[2] = (short)f2b(u0.z); a[3] = (short)f2b(u0.w);
        a[4] = (short)f2b(u1.x); a[5] = (short)f2b(u1.y);
        a[6] = (short)f2b(u1.z); a[7] = (short)f2b(u1.w);
        afrag[mt][kb] = a;
      }
    } else {
      const unsigned short* xp = (const unsigned short*)A.xraw + (size_t)nc * 128 + quad * 8;
      #pragma unroll
      for (int kb = 0; kb < 4; ++kb)
        afrag[mt][kb] = *(const bf8_t*)(xp + kb * 32);
    }
  }
  #pragma unroll
  for (int ct = 0; ct < 8; ++ct) {
    bf8_t bfrag[4];
    #pragma unroll
    for (int kb = 0; kb < 4; ++kb)
      bfrag[kb] = *(const bf8_t*)(Wf + ((ct * 4 + kb) * 64 + l) * 8);
    #pragma unroll
    for (int mt = 0; mt < 2; ++mt) {
      f4_t acc = {0.f, 0.f, 0.f, 0.f};
      #pragma unroll
      for (int kb = 0; kb < 4; ++kb)
        acc = __builtin_amdgcn_mfma_f32_16x16x32_bf16(afrag[mt][kb], bfrag[kb], acc, 0, 0, 0);
      #pragma unroll
      for (int r = 0; r < 4; ++r) {
        int node = m0 + mt * 16 + quad * 4 + r;
        if (node < n)
          A.hbufA[(size_t)node * 128 + ct * 16 + r16] = f2b(acc[r] * dv[mt][r]);
      }
    }
  }
}

template<int DW> struct UVec { unsigned int d[DW]; };
template<int DW>
__device__ __forceinline__ UVec<DW> uload(const unsigned int* p) {
  UVec<DW> r;
  if constexpr (DW == 4) { uint4 v = *(const uint4*)p; r.d[0]=v.x; r.d[1]=v.y; r.d[2]=v.z; r.d[3]=v.w; }
  else if constexpr (DW == 2) { uint2 v = *(const uint2*)p; r.d[0]=v.x; r.d[1]=v.y; }
  else { r.d[0] = *p; }
  return r;
}
template<int DW>
__device__ __forceinline__ void ustore(unsigned int* p, const UVec<DW>& v) {
  if constexpr (DW == 4) { *(uint4*)p = make_uint4(v.d[0], v.d[1], v.d[2], v.d[3]); }
  else if constexpr (DW == 2) { *(uint2*)p = make_uint2(v.d[0], v.d[1]); }
  else { *p = v.d[0]; }
}

template<int FIN, int FOUT, int LPG>
__device__ void aggemm_body(const unsigned short* __restrict__ Hin,
    const int* __restrict__ row_ptr, const int* __restrict__ csr_src,
    const float* __restrict__ dinv, const unsigned short* __restrict__ bias,
    const unsigned short* __restrict__ Wf, unsigned short* __restrict__ Hout,
    int n, int task, unsigned char* smemraw) {
  constexpr int DW  = FIN / LPG / 2;
  constexpr int NPB = 256 / LPG;
  constexpr int LD  = FIN + 8;
  constexpr int KB  = FIN / 32;
  constexpr int CT  = FOUT / 16;
  constexpr int MT  = NPB / 16;
  unsigned short* T = (unsigned short*)smemraw;
  __syncthreads();
  const int r = threadIdx.x / LPG, l = threadIdx.x % LPG;
  const int node0 = task * NPB;
  const int g = node0 + r;
  const unsigned int* H2 = (const unsigned int*)Hin;
  UVec<DW> o;
  #pragma unroll
  for (int d = 0; d < DW; ++d) o.d[d] = 0u;
  if (g < n) {
    float a[2 * DW];
    UVec<DW> hv = uload<DW>(H2 + (size_t)g * (FIN / 2) + l * DW);
    #pragma unroll
    for (int d = 0; d < DW; ++d) {          // self term H'[g]
      a[2*d]   = b2f(hv.d[d] & 0xffffu);
      a[2*d+1] = b2f(hv.d[d] >> 16);
    }
    const int e0 = row_ptr[g], e1 = row_ptr[g + 1];
    for (int base = e0; base < e1; base += LPG) {
      int cnt = e1 - base < LPG ? e1 - base : LPG;
      int my = csr_src[(base + l < e1) ? (base + l) : (e1 - 1)];
      for (int j = 0; j < cnt; ++j) {
        int s = __shfl(my, j, LPG);
        UVec<DW> v = uload<DW>(H2 + (size_t)s * (FIN / 2) + l * DW);
        #pragma unroll
        for (int d = 0; d < DW; ++d) {
          a[2*d]   += b2f(v.d[d] & 0xffffu);
          a[2*d+1] += b2f(v.d[d] >> 16);
        }
      }
    }
    float di = dinv[g];
    UVec<DW> bb = uload<DW>((const unsigned int*)bias + l * DW);
    #pragma unroll
    for (int d = 0; d < DW; ++d) {
      float lo = fmaxf(fmaf(a[2*d],   di, b2f(bb.d[d] & 0xffffu)), 0.f);
      float hi = fmaxf(fmaf(a[2*d+1], di, b2f(bb.d[d] >> 16)), 0.f);
      o.d[d] = (unsigned int)f2b(lo) | ((unsigned int)f2b(hi) << 16);
    }
  }
  ustore<DW>((unsigned int*)&T[r * LD + l * DW * 2], o);
  __syncthreads();
  const int w = threadIdx.x >> 6;
  if (w < MT * CT && node0 < n) {
    const int mt = w / CT, ct = w % CT;
    const int ll = threadIdx.x & 63;
    const int r16 = ll & 15, quad = ll >> 4;
    float dvv[4];
    #pragma unroll
    for (int rr = 0; rr < 4; ++rr) {
      int nd = node0 + mt * 16 + quad * 4 + rr;
      dvv[rr] = dinv[nd < n ? nd : n - 1];
    }
    bf8_t afrag[KB], bfrag[KB];
    #pragma unroll
    for (int kb = 0; kb < KB; ++kb) {
      afrag[kb] = *(const bf8_t*)(&T[(mt * 16 + r16) * LD + quad * 8 + kb * 32]);
      bfrag[kb] = *(const bf8_t*)(Wf + ((ct * KB + kb) * 64 + ll) * 8);
    }
    f4_t acc = {0.f, 0.f, 0.f, 0.f};
    #pragma unroll
    for (int kb = 0; kb < KB; ++kb)
      acc = __builtin_amdgcn_mfma_f32_16x16x32_bf16(afrag[kb], bfrag[kb], acc, 0, 0, 0);
    #pragma unroll
    for (int rr = 0; rr < 4; ++rr) {
      int node = node0 + mt * 16 + quad * 4 + rr;
      if (node < n)
        Hout[(size_t)node * FOUT + ct * 16 + r16] = f2b(acc[rr] * dvv[rr]);
    }
  }
}

__device__ void agg_pool_body(const MegaArgs& A, const unsigned short* __restrict__ Hin,
    const unsigned short* __restrict__ bias, int task, unsigned char* smemraw) {
  float* acc  = (float*)smemraw;
  float* ccnt = (float*)(smemraw + N_GRAPHS * 16 * 4);
  __syncthreads();
  for (int i = threadIdx.x; i < N_GRAPHS * 16; i += 256) acc[i] = 0.f;
  if (threadIdx.x < N_GRAPHS) ccnt[threadIdx.x] = 0.f;
  __syncthreads();
  const int n = A.N;
  const int r = threadIdx.x >> 3, l = threadIdx.x & 7;
  const int g = task * 32 + r;
  if (g < n) {
    const unsigned int* H2 = (const unsigned int*)Hin;
    unsigned int hv = H2[(size_t)g * 8 + l];
    float a0 = b2f(hv & 0xffffu);
    float a1 = b2f(hv >> 16);
    const int e0 = A.row_ptr[g], e1 = A.row_ptr[g + 1];
    for (int base = e0; base < e1; base += 8) {
      int cnt2 = e1 - base < 8 ? e1 - base : 8;
      int my = A.csr_src[(base + l < e1) ? (base + l) : (e1 - 1)];
      for (int j = 0; j < cnt2; ++j) {
        int s = __shfl(my, j, 8);
        unsigned int v = H2[(size_t)s * 8 + l];
        a0 += b2f(v & 0xffffu);
        a1 += b2f(v >> 16);
      }
    }
    float di = A.dinv[g];
    unsigned int bb = ((const unsigned int*)bias)[l];
    a0 = fmaxf(fmaf(a0, di, b2f(bb & 0xffffu)), 0.f);
    a1 = fmaxf(fmaf(a1, di, b2f(bb >> 16)), 0.f);
    int gb = A.b32[g];
    atomicAdd(&acc[gb * 16 + l * 2 + 0], a0);
    atomicAdd(&acc[gb * 16 + l * 2 + 1], a1);
    if (l == 0) atomicAdd(&ccnt[gb], 1.f);
  }
  __syncthreads();
  for (int i = threadIdx.x; i < N_GRAPHS * 16; i += 256)
    if (acc[i] != 0.f) atomicAdd(&A.pooled[i], acc[i]);
  if (threadIdx.x < N_GRAPHS && ccnt[threadIdx.x] != 0.f)
    atomicAdd(&A.cntf[threadIdx.x], ccnt[threadIdx.x]);
}

__device__ void final_body(const MegaArgs& A) {
  int f32;
  block_detect(A.xraw, nullptr, &f32, nullptr);
  const unsigned short* Wlin = A.wcan + WOFF[8];
  const unsigned short* blin = A.wcan + WOFF[9];
  for (int id = threadIdx.x; id < N_GRAPHS * N_CLASSES; id += 256) {
    int g = id / N_CLASSES, c = id - g * N_CLASSES;
    float inv = 1.0f / fmaxf(A.cntf[g], 1.0f);
    float a = b2f(blin[c]);
    #pragma unroll
    for (int f = 0; f < 16; ++f)
      a = fmaf(A.pooled[g * 16 + f] * inv, b2f(Wlin[f * N_CLASSES + c]), a);
    if (f32) ((float*)A.out)[id] = a;
    else     ((unsigned short*)A.out)[id] = f2b(a);
  }
}

// (256,4): VGPR cap 128 — R12's (256,8) capped at 32 and spilled the
// aggemm gather state to scratch (414 MB traffic). Bodies need ~52-80.
__global__ __launch_bounds__(256, 4) void gcn_mega(MegaArgs A) {
  __shared__ __align__(16) unsigned char smem[4608];
  cg::grid_group grid = cg::this_grid();
  const int bid = blockIdx.x, G = gridDim.x;

  for (int i = bid * 256 + threadIdx.x; i < A.nzd; i += G * 256) A.zbase_i[i] = 0;
  grid.sync();

  for (int t = bid; t < A.BW + A.BB + A.BEc; t += G) cvt_task(A, t);
  grid.sync();

  if (bid < A.nbS) scan_task(A, bid);
  grid.sync();

  for (int t = bid; t < A.BEc + A.G1; t += G) fill_gemm1_task(A, t);
  grid.sync();

  {
    const int T1 = (A.N + 15) / 16;
    for (int t = bid; t < T1; t += G)
      aggemm_body<128, 64, 16>(A.hbufA, A.row_ptr, A.csr_src, A.dinv,
          A.wcan + WOFF[1], A.wcan + WOFF[2], A.hbufB, A.N, t, smem);
  }
  grid.sync();

  {
    const int T2 = (A.N + 31) / 32;
    for (int t = bid; t < T2; t += G)
      aggemm_body<64, 32, 8>(A.hbufB, A.row_ptr, A.csr_src, A.dinv,
          A.wcan + WOFF[3], A.wcan + WOFF[4], A.hbufA, A.N, t, smem);
  }
  grid.sync();

  {
    const int T3 = (A.N + 31) / 32;
    for (int t = bid; t < T3; t += G)
      aggemm_body<32, 16, 8>(A.hbufA, A.row_ptr, A.csr_src, A.dinv,
          A.wcan + WOFF[5], A.wcan + WOFF[6], A.hbufB, A.N, t, smem);
  }
  grid.sync();

  {
    const int TP = (A.N + 31) / 32;
    for (int t = bid; t < TP; t += G)
      agg_pool_body(A, A.hbufB, A.wcan + WOFF[7], t, smem);
  }
  grid.sync();

  if (bid == 0) final_body(A);
}

extern "C" void kernel_launch(void* const* d_in, const int* in_sizes, int n_in,
                              void* d_out, int out_size, void* d_ws, size_t ws_size,
                              hipStream_t stream) {
  const unsigned int* xraw = (const unsigned int*)d_in[0];
  const int* eraw          = (const int*)d_in[1];
  const int* braw          = (const int*)d_in[2];

  const int N = in_sizes[2];
  const int E = in_sizes[1] / 2;
  const int nbS = (N + 255) / 256;

  char* p = (char*)d_ws;
  auto alloc = [&](size_t bytes) -> void* {
    void* r = (void*)p;
    p += (bytes + 255) & ~(size_t)255;
    return r;
  };
  const size_t off_desc = ((size_t)N * 4 + 255) & ~(size_t)255;
  const size_t off_pool = (off_desc + (size_t)nbS * 8 + 255) & ~(size_t)255;
  const size_t ztotal   = off_pool + (N_GRAPHS * 16 + N_GRAPHS) * 4;
  char* zbase = (char*)alloc(ztotal);
  int*   deg    = (int*)zbase;
  unsigned long long* desc = (unsigned long long*)(zbase + off_desc);
  float* pooled = (float*)(zbase + off_pool);
  float* cntf   = pooled + N_GRAPHS * 16;

  int*   row_ptr  = (int*)  alloc((size_t)(N + 1) * 4);
  int*   cursor   = (int*)  alloc((size_t)N * 4);
  float* dinv     = (float*)alloc((size_t)N * 4);
  int*   batch32  = (int*)  alloc((size_t)N * 4);
  int*   csr_src  = (int*)  alloc((size_t)E * 4);
  unsigned short* wcan  = (unsigned short*)alloc((size_t)WTOTAL * 2);
  unsigned short* hbufA = (unsigned short*)alloc((size_t)N * 128 * 2);
  unsigned short* hbufB = (unsigned short*)alloc((size_t)N * 128 * 2);

  MegaArgs ma;
  ma.xraw = xraw; ma.eraw = eraw; ma.braw = braw;
  for (int i = 0; i < 10; ++i) ma.wp.p[i] = d_in[3 + i];
  ma.wcan = wcan; ma.b32 = batch32;
  ma.zbase_i = (int*)zbase; ma.nzd = (int)(ztotal / 4);
  ma.deg = deg; ma.desc = desc;
  ma.row_ptr = row_ptr; ma.cursor = cursor; ma.dinv = dinv;
  ma.csr_src = csr_src; ma.hbufA = hbufA; ma.hbufB = hbufB;
  ma.pooled = pooled; ma.cntf = cntf; ma.out = d_out;
  ma.N = N; ma.E = E;
  ma.BW = (WTOTAL + 255) / 256;
  ma.BB = (N + 255) / 256;
  ma.BEc = (E + 255) / 256;
  ma.G1 = (N + 127) / 128;
  ma.nbS = nbS;

  int blocksPerCU = 0;
  hipOccupancyMaxActiveBlocksPerMultiprocessor(&blocksPerCU, (const void*)gcn_mega, 256, 0);
  if (blocksPerCU < 1) blocksPerCU = 1;
  int grid = blocksPerCU * 256;
  if (grid > 2048) grid = 2048;

  void* args[] = { &ma };
  hipLaunchCooperativeKernel((const void*)gcn_mega, dim3(grid), dim3(256),
                             args, 0, stream);
}

// Round 14
// 253.440 us; speedup vs baseline: 5.1201x; 3.2651x over previous
//
#include <hip/hip_runtime.h>
#include <hip/hip_bf16.h>

// GCN forward, MI355X. Round 14: revert to R9 (measured best, 240us) +
// LPG=16 tail aggregation (chain ceil(12/16)=1 batch, 2x grid).
//
//   memset(deg|desc|pooled|cnt)   [one region]
//   cvt_we    : W->bf16 (W1..W4 frag-major) | batch->i32 | degree count
//   scan      : one dispatch, decoupled lookback (packed state|value
//               atomics) -> row_ptr / cursor / dinv
//   fill_gemm1: block-range split — packed uint2 CSR fill | X@W1 MFMA
//   aggemm x3 : gather+bias+relu at the AGG's grid -> LDS tile -> MFMA
//   agg_pool  : last-layer gather (LPG=8) + LDS graph pool -> atomics
//   final     : 64x16 @ 16x10 linear
//
// Lessons: R5 fuse at agg's grid, never gemm's. R7 no per-block fences.
// R10/R11 scatter writeback ~ line ownership migration per store (entry
// size & sharding don't matter). R12 launch_bounds 2nd arg = VGPR cap in
// disguise. R12/R13 cooperative grid.sync costs a cross-XCD writeback per
// phase — worse than dispatch boundaries; mega-kernels lose on this chip.
// True inter-dispatch gap is only ~3us each (poison fill is in the timed
// window) — dispatch-count optimization is nearly exhausted.
//
// MFMA 16x16x32_bf16 layouts (verified): A[m=l&15][k=(l>>4)*8+j] (k-contig);
// B frag f at Wf[f*1024+l*16..+16] = B[kb*32+(l>>4)*8+j][ct*16+(l&15)];
// C/D col=l&15, row=(l>>4)*4+reg.

#define N_GRAPHS 64
#define N_CLASSES 10

typedef short bf8_t __attribute__((ext_vector_type(8)));
typedef float f4_t  __attribute__((ext_vector_type(4)));

__device__ __forceinline__ float b2f(unsigned int u) {
  return __uint_as_float(u << 16);
}
__device__ __forceinline__ unsigned short f2b(float f) {
  unsigned int x = __float_as_uint(f);
  x += 0x7fffu + ((x >> 16) & 1u);   // RNE (finite values only)
  return (unsigned short)(x >> 16);
}

// Per-block dtype detect; call with all 256 threads pre-divergence.
__device__ __forceinline__ void block_detect(const unsigned int* __restrict__ xraw,
    const unsigned int* __restrict__ eraw, int* f32, int* i64) {
  __shared__ int c_bf, c_nz;
  if (threadIdx.x == 0) { c_bf = 0; c_nz = 0; }
  __syncthreads();
  unsigned int d = xraw[threadIdx.x & 255];
  int e = (int)(((d & 0xffffu) >> 7) & 0xff);
  if (e >= 100 && e <= 140) atomicAdd(&c_bf, 1);
  if (eraw && threadIdx.x < 64 && eraw[2 * threadIdx.x + 1] != 0u) atomicAdd(&c_nz, 1);
  __syncthreads();
  *f32 = (c_bf < 150) ? 1 : 0;
  if (i64) *i64 = (c_nz == 0) ? 1 : 0;
}

struct WPtrs { const void* p[10]; };
static constexpr int WSEG[10] = {16384, 128, 8192, 64, 2048, 32, 512, 16, 160, 10};
static constexpr int WTOTAL   = 27546;
static constexpr int WOFF[10] = {0, 16384, 16512, 24704, 24768, 26816, 26848, 27360, 27376, 27536};

// blocks [0,BW): weights; [BW,BW+BB): batch; rest: degree count from eraw.
__global__ __launch_bounds__(256) void cvt_we_kernel(
    const unsigned int* __restrict__ xraw, WPtrs wp, unsigned short* __restrict__ wc,
    const int* __restrict__ braw, int* __restrict__ b32,
    const int* __restrict__ eraw, int* __restrict__ deg,
    int BW, int BB, int n, int E) {
  int f32, i64;
  block_detect(xraw, (const unsigned int*)eraw, &f32, &i64);
  const int bid = blockIdx.x;
  if (bid < BW) {
    int i = bid * 256 + threadIdx.x;
    if (i >= WTOTAL) return;
    int off = i, s = 0;
    #pragma unroll
    for (int t = 0; t < 10; ++t) {
      if (s == 0 && off >= WSEG[t]) { off -= WSEG[t]; } else if (s == 0) { s = t + 1; }
    }
    s -= 1;
    int soff = off;
    if ((s & 1) == 0 && s <= 6) {           // W1..W4 -> fragment-major
      int KB, FOUT;
      if (s == 0)      { KB = 4; FOUT = 128; }
      else if (s == 2) { KB = 4; FOUT = 64; }
      else if (s == 4) { KB = 2; FOUT = 32; }
      else             { KB = 1; FOUT = 16; }
      int j = off & 7, l = (off >> 3) & 63, f = off >> 9;
      int ct = f / KB, kb = f - ct * KB;
      int k = kb * 32 + ((l >> 4) << 3) + j;
      int nn = ct * 16 + (l & 15);
      soff = k * FOUT + nn;
    }
    const void* p = wp.p[s];
    wc[WOFF[s] + off] = f32 ? f2b(((const float*)p)[soff])
                            : ((const unsigned short*)p)[soff];
  } else if (bid < BW + BB) {
    int i = (bid - BW) * 256 + threadIdx.x;
    if (i < n) b32[i] = i64 ? braw[2 * i] : braw[i];
  } else {
    int e = (bid - BW - BB) * 256 + threadIdx.x;
    if (e >= E) return;
    int d = i64 ? eraw[2 * (E + e)] : eraw[E + e];
    atomicAdd(&deg[d], 1);
  }
}

// Single-dispatch decoupled-lookback scan (packed state|value atomics).
__global__ __launch_bounds__(256) void scan_kernel(const int* __restrict__ deg,
    int* __restrict__ row_ptr, int* __restrict__ cursor, float* __restrict__ dinv,
    unsigned long long* __restrict__ desc, int n) {
  __shared__ int ws[4];
  __shared__ int s_total;
  __shared__ unsigned int s_prev;
  const int b = blockIdx.x, tid = threadIdx.x, lane = tid & 63, wv = tid >> 6;
  const int i = b * 256 + tid;
  int v = (i < n) ? deg[i] : 0;
  int x = v;
  #pragma unroll
  for (int off = 1; off < 64; off <<= 1) {
    int y = __shfl_up(x, off, 64);
    if (lane >= off) x += y;
  }
  if (lane == 63) ws[wv] = x;
  __syncthreads();
  int wbase = 0;
  for (int w = 0; w < wv; ++w) wbase += ws[w];
  int incl = x + wbase;
  if (tid == 0) {
    int tot = ws[0] + ws[1] + ws[2] + ws[3];
    s_total = tot;
    unsigned long long st = (b == 0) ? (2ULL << 62) : (1ULL << 62);
    atomicExch(&desc[b], st | (unsigned long long)(unsigned int)tot);
    if (b == 0) s_prev = 0u;
  }
  __syncthreads();
  if (b > 0 && wv == 0) {
    unsigned int running = 0;
    int j = b - 1;
    while (true) {
      int idx = j - lane;
      unsigned long long dsc;
      if (idx >= 0) {
        do { dsc = atomicAdd(&desc[idx], 0ULL); } while ((dsc >> 62) == 0ULL);
      } else {
        dsc = (2ULL << 62);
      }
      unsigned long long ball = __ballot((dsc >> 62) == 2ULL);
      int fp = ball ? (__ffsll((unsigned long long)ball) - 1) : 64;
      unsigned int contrib = (lane <= fp) ? (unsigned int)(dsc & 0xffffffffULL) : 0u;
      #pragma unroll
      for (int o = 32; o; o >>= 1) contrib += __shfl_xor(contrib, o, 64);
      running += contrib;
      if (fp < 64) break;
      j -= 64;
    }
    if (lane == 0) {
      atomicExch(&desc[b], (2ULL << 62) |
                 (unsigned long long)(unsigned int)(running + (unsigned int)s_total));
      s_prev = running;
    }
  }
  __syncthreads();
  int tot = (int)s_prev + incl;
  if (i < n) {
    row_ptr[i + 1] = tot;
    cursor[i] = tot - v;
    dinv[i] = rsqrtf((float)v + 1.0f);
  }
  if (i == 0) row_ptr[0] = 0;
}

// Merged: blocks [0,BE) fill packed CSR from raw edges; rest X@W1 via MFMA.
__global__ __launch_bounds__(256) void fill_gemm1_kernel(
    const int* __restrict__ eraw, const unsigned int* __restrict__ xraw,
    int* __restrict__ cursor, const float* __restrict__ dinv,
    uint2* __restrict__ csr,
    const unsigned short* __restrict__ Wf, unsigned short* __restrict__ H,
    int BE, int n, int E) {
  int f32, i64;
  block_detect(xraw, (const unsigned int*)eraw, &f32, &i64);
  if (blockIdx.x < BE) {
    int e = blockIdx.x * 256 + threadIdx.x;
    if (e < E) {
      int s, d;
      if (i64) { s = eraw[2 * e]; d = eraw[2 * (E + e)]; }
      else     { s = eraw[e];     d = eraw[E + e]; }
      int pos = atomicAdd(&cursor[d], 1);
      uint2 v;
      v.x = (unsigned int)s;
      v.y = __float_as_uint(dinv[s] * dinv[d]);
      csr[pos] = v;
    }
    return;
  }
  const int b2 = blockIdx.x - BE;
  const int l = threadIdx.x & 63;
  const int r16 = l & 15, quad = l >> 4;
  const int m0 = (b2 * 4 + (threadIdx.x >> 6)) * 32;
  if (m0 >= n) return;
  bf8_t afrag[2][4];
  #pragma unroll
  for (int mt = 0; mt < 2; ++mt) {
    int node = m0 + mt * 16 + r16;
    int nc = node < n ? node : n - 1;
    if (f32) {
      const float* xp = (const float*)xraw + (size_t)nc * 128 + quad * 8;
      #pragma unroll
      for (int kb = 0; kb < 4; ++kb) {
        const float4* p4 = (const float4*)(xp + kb * 32);
        float4 u0 = p4[0], u1 = p4[1];
        bf8_t a;
        a[0] = (short)f2b(u0.x); a[1] = (short)f2b(u0.y);
        a[2] = (short)f2b(u0.z); a[3] = (short)f2b(u0.w);
        a[4] = (short)f2b(u1.x); a[5] = (short)f2b(u1.y);
        a[6] = (short)f2b(u1.z); a[7] = (short)f2b(u1.w);
        afrag[mt][kb] = a;
      }
    } else {
      const unsigned short* xp = (const unsigned short*)xraw + (size_t)nc * 128 + quad * 8;
      #pragma unroll
      for (int kb = 0; kb < 4; ++kb)
        afrag[mt][kb] = *(const bf8_t*)(xp + kb * 32);
    }
  }
  #pragma unroll
  for (int ct = 0; ct < 8; ++ct) {
    bf8_t bfrag[4];
    #pragma unroll
    for (int kb = 0; kb < 4; ++kb)
      bfrag[kb] = *(const bf8_t*)(Wf + ((ct * 4 + kb) * 64 + l) * 8);
    #pragma unroll
    for (int mt = 0; mt < 2; ++mt) {
      f4_t acc = {0.f, 0.f, 0.f, 0.f};
      #pragma unroll
      for (int kb = 0; kb < 4; ++kb)
        acc = __builtin_amdgcn_mfma_f32_16x16x32_bf16(afrag[mt][kb], bfrag[kb], acc, 0, 0, 0);
      #pragma unroll
      for (int r = 0; r < 4; ++r) {
        int node = m0 + mt * 16 + quad * 4 + r;
        if (node < n)
          H[(size_t)node * 128 + ct * 16 + r16] = f2b(acc[r]);
      }
    }
  }
}

// ---- generic per-lane vector of DW dwords ----
template<int DW> struct UVec { unsigned int d[DW]; };
template<int DW>
__device__ __forceinline__ UVec<DW> uload(const unsigned int* p) {
  UVec<DW> r;
  if constexpr (DW == 4) { uint4 v = *(const uint4*)p; r.d[0]=v.x; r.d[1]=v.y; r.d[2]=v.z; r.d[3]=v.w; }
  else if constexpr (DW == 2) { uint2 v = *(const uint2*)p; r.d[0]=v.x; r.d[1]=v.y; }
  else { r.d[0] = *p; }
  return r;
}
template<int DW>
__device__ __forceinline__ void ustore(unsigned int* p, const UVec<DW>& v) {
  if constexpr (DW == 4) { *(uint4*)p = make_uint4(v.d[0], v.d[1], v.d[2], v.d[3]); }
  else if constexpr (DW == 2) { *(uint2*)p = make_uint2(v.d[0], v.d[1]); }
  else { *p = v.d[0]; }
}

// Fused agg(FIN, bias, relu) -> LDS tile -> MFMA @ Wf(FIN x FOUT) -> Hout.
// Grid = agg's grid (NPB=256/LPG nodes/block), occupancy preserved.
template<int FIN, int FOUT, int LPG>
__global__ __launch_bounds__(256) void aggemm_kernel(
    const unsigned short* __restrict__ Hin,
    const int* __restrict__ row_ptr, const uint2* __restrict__ csr,
    const float* __restrict__ dinv, const unsigned short* __restrict__ bias,
    const unsigned short* __restrict__ Wf, unsigned short* __restrict__ Hout, int n) {
  constexpr int DW  = FIN / LPG / 2;
  constexpr int NPB = 256 / LPG;
  constexpr int LD  = FIN + 8;
  constexpr int KB  = FIN / 32;
  constexpr int CT  = FOUT / 16;
  constexpr int MT  = NPB / 16;
  __shared__ unsigned short T[NPB * LD];
  const int r = threadIdx.x / LPG, l = threadIdx.x % LPG;
  const int node0 = blockIdx.x * NPB;
  const int g = node0 + r;
  const unsigned int* H2 = (const unsigned int*)Hin;
  UVec<DW> o;
  #pragma unroll
  for (int d = 0; d < DW; ++d) o.d[d] = 0u;
  if (g < n) {
    float di = dinv[g];
    float c0 = di * di;
    float a[2 * DW];
    UVec<DW> hv = uload<DW>(H2 + (size_t)g * (FIN / 2) + l * DW);
    #pragma unroll
    for (int d = 0; d < DW; ++d) {
      a[2*d]   = b2f(hv.d[d] & 0xffffu) * c0;
      a[2*d+1] = b2f(hv.d[d] >> 16) * c0;
    }
    const int e0 = row_ptr[g], e1 = row_ptr[g + 1];
    for (int base = e0; base < e1; base += LPG) {
      int cnt = e1 - base < LPG ? e1 - base : LPG;
      uint2 my = csr[(base + l < e1) ? (base + l) : (e1 - 1)];
      for (int j = 0; j < cnt; ++j) {
        int s = __shfl((int)my.x, j, LPG);
        float c = __uint_as_float(__shfl((int)my.y, j, LPG));
        UVec<DW> v = uload<DW>(H2 + (size_t)s * (FIN / 2) + l * DW);
        #pragma unroll
        for (int d = 0; d < DW; ++d) {
          a[2*d]   = fmaf(b2f(v.d[d] & 0xffffu), c, a[2*d]);
          a[2*d+1] = fmaf(b2f(v.d[d] >> 16), c, a[2*d+1]);
        }
      }
    }
    UVec<DW> bb = uload<DW>((const unsigned int*)bias + l * DW);
    #pragma unroll
    for (int d = 0; d < DW; ++d) {
      float lo = fmaxf(a[2*d]   + b2f(bb.d[d] & 0xffffu), 0.f);
      float hi = fmaxf(a[2*d+1] + b2f(bb.d[d] >> 16), 0.f);
      o.d[d] = (unsigned int)f2b(lo) | ((unsigned int)f2b(hi) << 16);
    }
  }
  ustore<DW>((unsigned int*)&T[r * LD + l * DW * 2], o);
  __syncthreads();
  const int w = threadIdx.x >> 6;
  if (w < MT * CT && node0 < n) {
    const int mt = w / CT, ct = w % CT;
    const int ll = threadIdx.x & 63;
    const int r16 = ll & 15, quad = ll >> 4;
    bf8_t afrag[KB], bfrag[KB];
    #pragma unroll
    for (int kb = 0; kb < KB; ++kb) {
      afrag[kb] = *(const bf8_t*)(&T[(mt * 16 + r16) * LD + quad * 8 + kb * 32]);
      bfrag[kb] = *(const bf8_t*)(Wf + ((ct * KB + kb) * 64 + ll) * 8);
    }
    f4_t acc = {0.f, 0.f, 0.f, 0.f};
    #pragma unroll
    for (int kb = 0; kb < KB; ++kb)
      acc = __builtin_amdgcn_mfma_f32_16x16x32_bf16(afrag[kb], bfrag[kb], acc, 0, 0, 0);
    #pragma unroll
    for (int rr = 0; rr < 4; ++rr) {
      int node = node0 + mt * 16 + quad * 4 + rr;
      if (node < n)
        Hout[(size_t)node * FOUT + ct * 16 + r16] = f2b(acc[rr]);
    }
  }
}

// Fused last-layer agg + mean-pool. LPG=8, 32 nodes/block.
__global__ __launch_bounds__(256) void agg_pool_kernel(
    const unsigned short* __restrict__ Hin,
    const int* __restrict__ row_ptr, const uint2* __restrict__ csr,
    const float* __restrict__ dinv, const unsigned short* __restrict__ bias,
    const int* __restrict__ batch, float* __restrict__ pooled,
    float* __restrict__ cnt, int n) {
  __shared__ float acc[N_GRAPHS * 16];
  __shared__ float ccnt[N_GRAPHS];
  for (int i = threadIdx.x; i < N_GRAPHS * 16; i += 256) acc[i] = 0.f;
  if (threadIdx.x < N_GRAPHS) ccnt[threadIdx.x] = 0.f;
  __syncthreads();
  const int r = threadIdx.x >> 3, l = threadIdx.x & 7;
  const int g = blockIdx.x * 32 + r;
  if (g < n) {
    const unsigned int* H2 = (const unsigned int*)Hin;
    float di = dinv[g];
    float c0 = di * di;
    unsigned int hv = H2[(size_t)g * 8 + l];
    float a0 = b2f(hv & 0xffffu) * c0;
    float a1 = b2f(hv >> 16) * c0;
    const int e0 = row_ptr[g], e1 = row_ptr[g + 1];
    for (int base = e0; base < e1; base += 8) {
      int cnt2 = e1 - base < 8 ? e1 - base : 8;
      uint2 my = csr[(base + l < e1) ? (base + l) : (e1 - 1)];
      for (int j = 0; j < cnt2; ++j) {
        int s = __shfl((int)my.x, j, 8);
        float c = __uint_as_float(__shfl((int)my.y, j, 8));
        unsigned int v = H2[(size_t)s * 8 + l];
        a0 = fmaf(b2f(v & 0xffffu), c, a0);
        a1 = fmaf(b2f(v >> 16), c, a1);
      }
    }
    unsigned int bb = ((const unsigned int*)bias)[l];
    a0 = fmaxf(a0 + b2f(bb & 0xffffu), 0.f);
    a1 = fmaxf(a1 + b2f(bb >> 16), 0.f);
    int gb = batch[g];
    atomicAdd(&acc[gb * 16 + l * 2 + 0], a0);
    atomicAdd(&acc[gb * 16 + l * 2 + 1], a1);
    if (l == 0) atomicAdd(&ccnt[gb], 1.f);
  }
  __syncthreads();
  for (int i = threadIdx.x; i < N_GRAPHS * 16; i += 256)
    if (acc[i] != 0.f) atomicAdd(&pooled[i], acc[i]);
  if (threadIdx.x < N_GRAPHS && ccnt[threadIdx.x] != 0.f)
    atomicAdd(&cnt[threadIdx.x], ccnt[threadIdx.x]);
}

__global__ __launch_bounds__(256) void final_kernel(const float* __restrict__ pooled,
    const float* __restrict__ cnt, const unsigned short* __restrict__ wc,
    void* __restrict__ out, const unsigned int* __restrict__ xraw) {
  int f32;
  block_detect(xraw, nullptr, &f32, nullptr);
  int id = blockIdx.x * 256 + threadIdx.x;
  if (id >= N_GRAPHS * N_CLASSES) return;
  const unsigned short* Wlin = wc + WOFF[8];
  const unsigned short* blin = wc + WOFF[9];
  int g = id / N_CLASSES, c = id - g * N_CLASSES;
  float inv = 1.0f / fmaxf(cnt[g], 1.0f);
  float a = b2f(blin[c]);
  #pragma unroll
  for (int f = 0; f < 16; ++f)
    a = fmaf(pooled[g * 16 + f] * inv, b2f(Wlin[f * N_CLASSES + c]), a);
  if (f32) ((float*)out)[id] = a;
  else     ((unsigned short*)out)[id] = f2b(a);
}

extern "C" void kernel_launch(void* const* d_in, const int* in_sizes, int n_in,
                              void* d_out, int out_size, void* d_ws, size_t ws_size,
                              hipStream_t stream) {
  const unsigned int* xraw = (const unsigned int*)d_in[0];
  const int* eraw          = (const int*)d_in[1];
  const int* braw          = (const int*)d_in[2];

  const int N = in_sizes[2];
  const int E = in_sizes[1] / 2;
  const int nb = (N + 255) / 256;

  char* p = (char*)d_ws;
  auto alloc = [&](size_t bytes) -> void* {
    void* r = (void*)p;
    p += (bytes + 255) & ~(size_t)255;
    return r;
  };
  // zero region: deg | desc | pooled | cnt  (single memset)
  const size_t off_desc = ((size_t)N * 4 + 255) & ~(size_t)255;
  const size_t off_pool = (off_desc + (size_t)nb * 8 + 255) & ~(size_t)255;
  const size_t ztotal   = off_pool + (N_GRAPHS * 16 + N_GRAPHS) * 4;
  char* zbase = (char*)alloc(ztotal);
  int*   deg    = (int*)zbase;
  unsigned long long* desc = (unsigned long long*)(zbase + off_desc);
  float* pooled = (float*)(zbase + off_pool);
  float* cntf   = pooled + N_GRAPHS * 16;

  int*   row_ptr  = (int*)  alloc((size_t)(N + 1) * 4);
  int*   cursor   = (int*)  alloc((size_t)N * 4);
  float* dinv     = (float*)alloc((size_t)N * 4);
  int*   batch32  = (int*)  alloc((size_t)N * 4);
  uint2* csr      = (uint2*)alloc((size_t)E * 8);
  unsigned short* wcan  = (unsigned short*)alloc((size_t)WTOTAL * 2);
  unsigned short* hbufA = (unsigned short*)alloc((size_t)N * 128 * 2);
  unsigned short* hbufB = (unsigned short*)alloc((size_t)N * 128 * 2);

  hipMemsetAsync(zbase, 0, ztotal, stream);

  WPtrs wp;
  for (int i = 0; i < 10; ++i) wp.p[i] = d_in[3 + i];

  const int BW = (WTOTAL + 255) / 256;
  const int BB = nb;
  const int BE = (E + 255) / 256;
  cvt_we_kernel<<<BW + BB + BE, 256, 0, stream>>>(xraw, wp, wcan, braw, batch32,
      eraw, deg, BW, BB, N, E);

  scan_kernel<<<nb, 256, 0, stream>>>(deg, row_ptr, cursor, dinv, desc, N);

  const unsigned short* W1 = wcan + WOFF[0];
  const unsigned short* b1 = wcan + WOFF[1];
  const unsigned short* W2 = wcan + WOFF[2];
  const unsigned short* b2 = wcan + WOFF[3];
  const unsigned short* W3 = wcan + WOFF[4];
  const unsigned short* b3 = wcan + WOFF[5];
  const unsigned short* W4 = wcan + WOFF[6];
  const unsigned short* b4 = wcan + WOFF[7];

  const int G1 = (N + 127) / 128;
  fill_gemm1_kernel<<<BE + G1, 256, 0, stream>>>(eraw, xraw, cursor, dinv, csr,
      W1, hbufA, BE, N, E);

  aggemm_kernel<128, 64, 16><<<(N + 15) / 16, 256, 0, stream>>>(
      hbufA, row_ptr, csr, dinv, b1, W2, hbufB, N);
  aggemm_kernel<64, 32, 16><<<(N + 15) / 16, 256, 0, stream>>>(
      hbufB, row_ptr, csr, dinv, b2, W3, hbufA, N);
  aggemm_kernel<32, 16, 16><<<(N + 15) / 16, 256, 0, stream>>>(
      hbufA, row_ptr, csr, dinv, b3, W4, hbufB, N);
  agg_pool_kernel<<<(N + 31) / 32, 256, 0, stream>>>(hbufB, row_ptr, csr, dinv, b4,
      batch32, pooled, cntf, N);

  final_kernel<<<(N_GRAPHS * N_CLASSES + 255) / 256, 256, 0, stream>>>(pooled, cntf, wcan, d_out, xraw);
}